// Round 1
// baseline (276.262 us; speedup 1.0000x reference)
//
#include <hip/hip_runtime.h>

// Problem constants
#define BB 2
#define NN 4
#define DD 48
#define HH 28
#define WW 60
#define CC 64
#define NXg 192
#define NYg 192
#define NZg 1
#define DOWNS 8

constexpr int PTS    = BB * NN * DD * HH * WW;       // 645120 points
constexpr int NCELLS = BB * NZg * NYg * NXg;         // 73728 output cells
constexpr int NYX    = NYg * NXg;                    // 36864 cells per batch-plane

// ---------------------------------------------------------------------------
// Fused kernel: per-point geometry -> cell id, then wave-cooperative
// run-merged atomic scatter of the 64-channel x-row into cell-major outT.
//
// Each wave = 64 consecutive points (one (b,n) per wave: 80640 % 64 == 0).
// Lane l computes geometry for point base+l (f64 path kept VERBATIM from the
// verified kernel: absmax 0.125 passes). Then a wave-uniform ballot loop:
// broadcast cell of each valid lane, coalesced 256B x-row load (lane = ch),
// accumulate in registers while consecutive points share a cell (near-depth
// runs), one atomicAdd per run. outT[cell][ch] is 256B-contiguous per row,
// so each atomic wave touches 4 lines, not 64.
// ---------------------------------------------------------------------------
__global__ void __launch_bounds__(256)
scatter_kernel(const float* __restrict__ x,
               const float* __restrict__ intr,
               const float* __restrict__ pose,
               float* __restrict__ outT) {
    int tid  = threadIdx.x;
    int lane = tid & 63;
    int p    = blockIdx.x * 256 + tid;               // grid is exact multiple

    int w = p % WW;
    int t = p / WW;
    int h = t % HH; t /= HH;
    int d = t % DD; t /= DD;
    int n = t % NN;
    int b = t / NN;

    const float* K  = intr + (size_t)(b * NN + n) * 9;
    const float* Pm = pose + (size_t)(b * NN + n) * 16;

    double k00 = K[0], k01 = K[1], k02 = K[2];
    double k10 = K[3], k11 = K[4], k12 = K[5];
    double k20 = K[6], k21 = K[7], k22 = K[8];

    double det = k00 * (k11 * k22 - k12 * k21)
               - k01 * (k10 * k22 - k12 * k20)
               + k02 * (k10 * k21 - k11 * k20);
    double id = 1.0 / det;
    double i00 = (k11 * k22 - k12 * k21) * id;
    double i01 = (k02 * k21 - k01 * k22) * id;
    double i02 = (k01 * k12 - k02 * k11) * id;
    double i10 = (k12 * k20 - k10 * k22) * id;
    double i11 = (k00 * k22 - k02 * k20) * id;
    double i12 = (k02 * k10 - k00 * k12) * id;
    double i20 = (k10 * k21 - k11 * k20) * id;
    double i21 = (k01 * k20 - k00 * k21) * id;
    double i22 = (k00 * k11 - k01 * k10) * id;

    double r00 = Pm[0],  r01 = Pm[1],  r02 = Pm[2],  tx = Pm[3];
    double r10 = Pm[4],  r11 = Pm[5],  r12 = Pm[6],  ty = Pm[7];
    double r20 = Pm[8],  r21 = Pm[9],  r22 = Pm[10], tz = Pm[11];

    double c00 = r00 * i00 + r01 * i10 + r02 * i20;
    double c01 = r00 * i01 + r01 * i11 + r02 * i21;
    double c02 = r00 * i02 + r01 * i12 + r02 * i22;
    double c10 = r10 * i00 + r11 * i10 + r12 * i20;
    double c11 = r10 * i01 + r11 * i11 + r12 * i21;
    double c12 = r10 * i02 + r11 * i12 + r12 * i22;
    double c20 = r20 * i00 + r21 * i10 + r22 * i20;
    double c21 = r20 * i01 + r21 * i11 + r22 * i21;
    double c22 = r20 * i02 + r21 * i12 + r22 * i22;

    double u   = (double)w * ((double)(WW * DOWNS - 1) / (double)(WW - 1));
    double v   = (double)h * ((double)(HH * DOWNS - 1) / (double)(HH - 1));
    double dep = 2.0 + (double)d;
    double px = u * dep, py = v * dep, pz = dep;

    double gxf = (c00 * px + c01 * py + c02 * pz + tx) * 4.0 + 96.0;
    double gyf = (c10 * px + c11 * py + c12 * pz + ty) * 4.0 + 96.0;
    double gzf = ((c20 * px + c21 * py + c22 * pz + tz) + 10.0) / 20.0;

    int gx = (int)gxf;
    int gy = (int)gyf;
    int gz = (int)gzf;

    bool kept = (gx >= 0) & (gx < NXg) & (gy >= 0) & (gy < NYg) &
                (gz >= 0) & (gz < NZg);

    int cell = kept ? (((b * NZg + gz) * NYg + gy) * NXg + gx) : -1;

    // ---- wave-cooperative run-merged scatter ----
    unsigned long long mask = __ballot(cell >= 0);
    if (mask == 0ULL) return;                        // whole wave out of frustum

    int base = p - lane;                             // wave's first point
    float acc = 0.f;
    int   cur = -1;
    while (mask) {
        int ks = __ffsll((long long)mask) - 1;       // ascending lane order
        mask &= mask - 1ULL;
        int ck = __shfl(cell, ks);                   // wave-uniform
        float xv = x[(size_t)(base + ks) * CC + lane];   // coalesced 256B row
        if (ck != cur) {
            if (cur >= 0) atomicAdd(&outT[(size_t)cur * CC + lane], acc);
            cur = ck;
            acc = 0.f;
        }
        acc += xv;
    }
    atomicAdd(&outT[(size_t)cur * CC + lane], acc);  // cur >= 0 (mask nonempty)
}

// ---------------------------------------------------------------------------
// Transpose: outT [cell][ch] (cell-major) -> out [b][ch][yx] (channel-major).
// 64-cell x 64-ch LDS tile, padded to 65 floats: coalesced 256B reads AND
// writes, bank-conflict-free. Fully overwrites out, so no out memset needed.
// A 64-cell tile never straddles b (NYX % 64 == 0).
// ---------------------------------------------------------------------------
__global__ void __launch_bounds__(256)
transpose_kernel(const float* __restrict__ outT,
                 float* __restrict__ out) {
    __shared__ float tile[64][65];
    int tid      = threadIdx.x;
    int cellbase = blockIdx.x * 64;

    const float* src = outT + (size_t)cellbase * CC;
    #pragma unroll
    for (int i = 0; i < 16; ++i) {
        int idx = i * 256 + tid;                     // 0..4095, coalesced
        tile[idx >> 6][idx & 63] = src[idx];
    }
    __syncthreads();

    int bb     = cellbase / NYX;                     // uniform per block
    int yxbase = cellbase % NYX;
    float* dst = out + (size_t)bb * CC * NYX + yxbase;
    #pragma unroll
    for (int i = 0; i < 16; ++i) {
        int idx = i * 256 + tid;
        int ch  = idx >> 6;
        int cl  = idx & 63;                          // consecutive per wave
        dst[(size_t)ch * NYX + cl] = tile[cl][ch];   // stride-65 read: no conflicts
    }
}

// ---------------------------------------------------------------------------
extern "C" void kernel_launch(void* const* d_in, const int* in_sizes, int n_in,
                              void* d_out, int out_size, void* d_ws, size_t ws_size,
                              hipStream_t stream) {
    const float* x    = (const float*)d_in[0];
    const float* intr = (const float*)d_in[1];
    const float* pose = (const float*)d_in[2];
    float* out = (float*)d_out;

    float* outT = (float*)d_ws;                      // NCELLS*CC floats = 18.9 MB

    hipMemsetAsync(outT, 0, (size_t)NCELLS * CC * sizeof(float), stream);
    scatter_kernel<<<PTS / 256, 256, 0, stream>>>(x, intr, pose, outT);
    transpose_kernel<<<NCELLS / 64, 256, 0, stream>>>(outT, out);
}

// Round 2
// 270.555 us; speedup vs baseline: 1.0211x; 1.0211x over previous
//
#include <hip/hip_runtime.h>

// Problem constants
#define BB 2
#define NN 4
#define DD 48
#define HH 28
#define WW 60
#define CC 64
#define NXg 192
#define NYg 192
#define NZg 1
#define DOWNS 8

constexpr int PTS    = BB * NN * DD * HH * WW;       // 645120 points
constexpr int NCELLS = BB * NZg * NYg * NXg;         // 73728 output cells
constexpr int NYX    = NYg * NXg;                    // 36864 cells per batch-plane

// ---------------------------------------------------------------------------
// Setup: per-(b,n) f64 K-inverse + R*K^-1 combine, computed ONCE (8 threads)
// instead of once per point. Stored as 12 doubles per view:
// [c00 c01 c02 c10 c11 c12 c20 c21 c22 tx ty tz].
// ---------------------------------------------------------------------------
__global__ void setup_kernel(const float* __restrict__ intr,
                             const float* __restrict__ pose,
                             double* __restrict__ coef) {
    int i = threadIdx.x;
    if (i >= BB * NN) return;
    const float* K  = intr + (size_t)i * 9;
    const float* Pm = pose + (size_t)i * 16;

    double k00 = K[0], k01 = K[1], k02 = K[2];
    double k10 = K[3], k11 = K[4], k12 = K[5];
    double k20 = K[6], k21 = K[7], k22 = K[8];

    double det = k00 * (k11 * k22 - k12 * k21)
               - k01 * (k10 * k22 - k12 * k20)
               + k02 * (k10 * k21 - k11 * k20);
    double id = 1.0 / det;
    double i00 = (k11 * k22 - k12 * k21) * id;
    double i01 = (k02 * k21 - k01 * k22) * id;
    double i02 = (k01 * k12 - k02 * k11) * id;
    double i10 = (k12 * k20 - k10 * k22) * id;
    double i11 = (k00 * k22 - k02 * k20) * id;
    double i12 = (k02 * k10 - k00 * k12) * id;
    double i20 = (k10 * k21 - k11 * k20) * id;
    double i21 = (k01 * k20 - k00 * k21) * id;
    double i22 = (k00 * k11 - k01 * k10) * id;

    double r00 = Pm[0],  r01 = Pm[1],  r02 = Pm[2],  tx = Pm[3];
    double r10 = Pm[4],  r11 = Pm[5],  r12 = Pm[6],  ty = Pm[7];
    double r20 = Pm[8],  r21 = Pm[9],  r22 = Pm[10], tz = Pm[11];

    double* c = coef + (size_t)i * 12;
    c[0] = r00 * i00 + r01 * i10 + r02 * i20;
    c[1] = r00 * i01 + r01 * i11 + r02 * i21;
    c[2] = r00 * i02 + r01 * i12 + r02 * i22;
    c[3] = r10 * i00 + r11 * i10 + r12 * i20;
    c[4] = r10 * i01 + r11 * i11 + r12 * i21;
    c[5] = r10 * i02 + r11 * i12 + r12 * i22;
    c[6] = r20 * i00 + r21 * i10 + r22 * i20;
    c[7] = r20 * i01 + r21 * i11 + r22 * i21;
    c[8] = r20 * i02 + r21 * i12 + r22 * i22;
    c[9]  = tx;
    c[10] = ty;
    c[11] = tz;
}

// ---------------------------------------------------------------------------
// Fused scatter: light per-point geometry (affine in u,v,dep), then
// wave-cooperative scatter with 8-DEEP INDEPENDENT row loads per batch
// (vs round-1's serial one-load-per-iteration dependent loop).
// Per batch of 8 kept lanes: broadcast 8 cells, issue 8 coalesced 256B
// x-row loads (pipelined by the compiler — no inter-load deps), then a
// wave-uniform merge-and-flush (run-merge pays only at d<8, costs ~8
// scalar compares). One atomicAdd wave-op per run: 256B contiguous,
// 4 cache lines.
// ---------------------------------------------------------------------------
__global__ void __launch_bounds__(256)
scatter_kernel(const float* __restrict__ x,
               const double* __restrict__ coef,
               float* __restrict__ outT) {
    int tid  = threadIdx.x;
    int lane = tid & 63;
    int p    = blockIdx.x * 256 + tid;               // grid exact multiple

    int w  = p % WW;
    int t  = p / WW;
    int h  = t % HH; t /= HH;
    int d  = t % DD;
    int bn = t / DD;                                 // b*NN + n, wave-uniform
    int b  = bn / NN;

    const double* cf = coef + (size_t)bn * 12;

    double u   = (double)w * ((double)(WW * DOWNS - 1) / (double)(WW - 1));
    double v   = (double)h * ((double)(HH * DOWNS - 1) / (double)(HH - 1));
    double dep = 2.0 + (double)d;

    double rx = cf[0] * u + cf[1] * v + cf[2];
    double ry = cf[3] * u + cf[4] * v + cf[5];
    double rz = cf[6] * u + cf[7] * v + cf[8];

    double gxf = (rx * dep + cf[9])  * 4.0 + 96.0;
    double gyf = (ry * dep + cf[10]) * 4.0 + 96.0;
    double gzf = ((rz * dep + cf[11]) + 10.0) / 20.0;

    int gx = (int)gxf;
    int gy = (int)gyf;
    int gz = (int)gzf;

    bool kept = (gx >= 0) & (gx < NXg) & (gy >= 0) & (gy < NYg) &
                (gz >= 0) & (gz < NZg);

    int cell = kept ? (((b * NZg + gz) * NYg + gy) * NXg + gx) : -1;

    unsigned long long mask = __ballot(cell >= 0);
    if (mask == 0ULL) return;

    int base = p - lane;                             // wave's first point
    float acc = 0.f;
    int   cur = -1;

    while (mask) {
        int k[8], c[8];
        // branchless extraction of up to 8 set bits (ffsll(0)==0 -> k=-1;
        // 0 & (0-1) == 0 keeps mask stable at zero)
        #pragma unroll
        for (int j = 0; j < 8; ++j) {
            k[j] = __ffsll((long long)mask) - 1;
            mask &= mask - 1ULL;
        }
        #pragma unroll
        for (int j = 0; j < 8; ++j) {
            int kj = k[j] >= 0 ? k[j] : 0;
            int cj = __shfl(cell, kj);
            c[j] = k[j] >= 0 ? cj : -1;
        }
        // 8 independent coalesced row loads (padded slots load row 'base')
        float val[8];
        #pragma unroll
        for (int j = 0; j < 8; ++j) {
            int kj = k[j] >= 0 ? k[j] : 0;
            val[j] = x[(size_t)(base + kj) * CC + lane];
        }
        // wave-uniform merge-and-flush
        #pragma unroll
        for (int j = 0; j < 8; ++j) {
            if (c[j] < 0) continue;                  // uniform scalar branch
            if (c[j] == cur) {
                acc += val[j];
            } else {
                if (cur >= 0) atomicAdd(&outT[(size_t)cur * CC + lane], acc);
                cur = c[j];
                acc = val[j];
            }
        }
    }
    if (cur >= 0) atomicAdd(&outT[(size_t)cur * CC + lane], acc);
}

// ---------------------------------------------------------------------------
// Transpose: outT [cell][ch] -> out [b][ch][yx]. 64x64 LDS tile padded to
// 65: coalesced 256B reads AND writes, bank-conflict-free. Fully overwrites
// out (no out memset). A 64-cell tile never straddles b (NYX % 64 == 0).
// ---------------------------------------------------------------------------
__global__ void __launch_bounds__(256)
transpose_kernel(const float* __restrict__ outT,
                 float* __restrict__ out) {
    __shared__ float tile[64][65];
    int tid      = threadIdx.x;
    int cellbase = blockIdx.x * 64;

    const float* src = outT + (size_t)cellbase * CC;
    #pragma unroll
    for (int i = 0; i < 16; ++i) {
        int idx = i * 256 + tid;                     // coalesced
        tile[idx >> 6][idx & 63] = src[idx];
    }
    __syncthreads();

    int bb     = cellbase / NYX;                     // uniform per block
    int yxbase = cellbase % NYX;
    float* dst = out + (size_t)bb * CC * NYX + yxbase;
    #pragma unroll
    for (int i = 0; i < 16; ++i) {
        int idx = i * 256 + tid;
        int ch  = idx >> 6;
        int cl  = idx & 63;
        dst[(size_t)ch * NYX + cl] = tile[cl][ch];   // stride-65: no conflicts
    }
}

// ---------------------------------------------------------------------------
extern "C" void kernel_launch(void* const* d_in, const int* in_sizes, int n_in,
                              void* d_out, int out_size, void* d_ws, size_t ws_size,
                              hipStream_t stream) {
    const float* x    = (const float*)d_in[0];
    const float* intr = (const float*)d_in[1];
    const float* pose = (const float*)d_in[2];
    float* out = (float*)d_out;

    double* coef = (double*)d_ws;                    // 8*12 doubles = 768 B
    float*  outT = (float*)d_ws + 256;               // NCELLS*CC = 18.9 MB

    hipMemsetAsync(outT, 0, (size_t)NCELLS * CC * sizeof(float), stream);
    setup_kernel<<<1, 64, 0, stream>>>(intr, pose, coef);
    scatter_kernel<<<PTS / 256, 256, 0, stream>>>(x, coef, outT);
    transpose_kernel<<<NCELLS / 64, 256, 0, stream>>>(outT, out);
}

// Round 3
// 232.165 us; speedup vs baseline: 1.1899x; 1.1654x over previous
//
#include <hip/hip_runtime.h>

// Problem constants
#define BB 2
#define NN 4
#define DD 48
#define HH 28
#define WW 60
#define CC 64
#define NXg 192
#define NYg 192
#define NZg 1
#define DOWNS 8

constexpr int PTS    = BB * NN * DD * HH * WW;       // 645120 points
constexpr int QPTS   = PTS / NN;                     // 161280 (b,d,h,w) groups
constexpr int DHW    = DD * HH * WW;                 // 80640 per view
constexpr int NCELLS = BB * NZg * NYg * NXg;         // 73728 output cells
constexpr int NYX    = NYg * NXg;                    // 36864 cells per batch-plane

// ---------------------------------------------------------------------------
// Setup: per-(b,n) f64 K-inverse + R*K^-1 combine, once (8 threads).
// [c00 c01 c02 c10 c11 c12 c20 c21 c22 tx ty tz] per view.
// ---------------------------------------------------------------------------
__global__ void setup_kernel(const float* __restrict__ intr,
                             const float* __restrict__ pose,
                             double* __restrict__ coef) {
    int i = threadIdx.x;
    if (i >= BB * NN) return;
    const float* K  = intr + (size_t)i * 9;
    const float* Pm = pose + (size_t)i * 16;

    double k00 = K[0], k01 = K[1], k02 = K[2];
    double k10 = K[3], k11 = K[4], k12 = K[5];
    double k20 = K[6], k21 = K[7], k22 = K[8];

    double det = k00 * (k11 * k22 - k12 * k21)
               - k01 * (k10 * k22 - k12 * k20)
               + k02 * (k10 * k21 - k11 * k20);
    double id = 1.0 / det;
    double i00 = (k11 * k22 - k12 * k21) * id;
    double i01 = (k02 * k21 - k01 * k22) * id;
    double i02 = (k01 * k12 - k02 * k11) * id;
    double i10 = (k12 * k20 - k10 * k22) * id;
    double i11 = (k00 * k22 - k02 * k20) * id;
    double i12 = (k02 * k10 - k00 * k12) * id;
    double i20 = (k10 * k21 - k11 * k20) * id;
    double i21 = (k01 * k20 - k00 * k21) * id;
    double i22 = (k00 * k11 - k01 * k10) * id;

    double r00 = Pm[0],  r01 = Pm[1],  r02 = Pm[2],  tx = Pm[3];
    double r10 = Pm[4],  r11 = Pm[5],  r12 = Pm[6],  ty = Pm[7];
    double r20 = Pm[8],  r21 = Pm[9],  r22 = Pm[10], tz = Pm[11];

    double* c = coef + (size_t)i * 12;
    c[0] = r00 * i00 + r01 * i10 + r02 * i20;
    c[1] = r00 * i01 + r01 * i11 + r02 * i21;
    c[2] = r00 * i02 + r01 * i12 + r02 * i22;
    c[3] = r10 * i00 + r11 * i10 + r12 * i20;
    c[4] = r10 * i01 + r11 * i11 + r12 * i21;
    c[5] = r10 * i02 + r11 * i12 + r12 * i22;
    c[6] = r20 * i00 + r21 * i10 + r22 * i20;
    c[7] = r20 * i01 + r21 * i11 + r22 * i21;
    c[8] = r20 * i02 + r21 * i12 + r22 * i22;
    c[9]  = tx;
    c[10] = ty;
    c[11] = tz;
}

// ---------------------------------------------------------------------------
// Fused scatter over (b,d,h,w) GROUPS: each lane computes the 4 per-view
// cells at runtime. When all 4 agree (true for this input: broadcast K and
// pose), the 4 x-rows are summed in registers and scattered with ONE atomic
// run — 4x fewer atomics, the round-1/2 wall. Wave-uniform slow path keeps
// general correctness if views ever diverge.
// ---------------------------------------------------------------------------
__global__ void __launch_bounds__(128)
scatter_kernel(const float* __restrict__ x,
               const double* __restrict__ coef,
               float* __restrict__ outT) {
    int tid  = threadIdx.x;
    int lane = tid & 63;
    int q    = blockIdx.x * 128 + tid;               // grid exact multiple

    int w  = q % WW;
    int t  = q / WW;
    int h  = t % HH; t /= HH;
    int d  = t % DD;
    int b  = t / DD;                                 // wave-uniform (DHW%64==0)

    double u   = (double)w * ((double)(WW * DOWNS - 1) / (double)(WW - 1));
    double v   = (double)h * ((double)(HH * DOWNS - 1) / (double)(HH - 1));
    double dep = 2.0 + (double)d;

    int c4[4];
    #pragma unroll
    for (int n = 0; n < NN; ++n) {
        const double* cf = coef + (size_t)(b * NN + n) * 12;
        double rx = cf[0] * u + cf[1] * v + cf[2];
        double ry = cf[3] * u + cf[4] * v + cf[5];
        double rz = cf[6] * u + cf[7] * v + cf[8];
        double gxf = (rx * dep + cf[9])  * 4.0 + 96.0;
        double gyf = (ry * dep + cf[10]) * 4.0 + 96.0;
        double gzf = ((rz * dep + cf[11]) + 10.0) / 20.0;
        int gx = (int)gxf;
        int gy = (int)gyf;
        int gz = (int)gzf;
        bool kept = (gx >= 0) & (gx < NXg) & (gy >= 0) & (gy < NYg) &
                    (gz >= 0) & (gz < NZg);
        c4[n] = kept ? (((b * NZg + gz) * NYg + gy) * NXg + gx) : -1;
    }

    bool allsame = (c4[0] == c4[1]) & (c4[1] == c4[2]) & (c4[2] == c4[3]);

    int dhw_base = (q - lane) - b * DHW;             // wave-uniform
    int xb       = b * NN * DHW;                     // wave-uniform

    // ---- fast path: 4 views merged, one atomic run per cell-run ----
    unsigned long long fmask = __ballot(allsame && c4[0] >= 0);
    float acc = 0.f;
    int   cur = -1;
    while (fmask) {
        int k[8];
        #pragma unroll
        for (int j = 0; j < 8; ++j) {                // ffsll(0)==0 -> k=-1
            k[j] = __ffsll((long long)fmask) - 1;
            fmask &= fmask - 1ULL;
        }
        int cc[8];
        #pragma unroll
        for (int j = 0; j < 8; ++j) {
            int kj = k[j] >= 0 ? k[j] : 0;
            int cj = __shfl(c4[0], kj);
            cc[j] = k[j] >= 0 ? cj : -1;
        }
        float val[8];
        #pragma unroll
        for (int j = 0; j < 8; ++j) {                // 32 independent loads
            int kj  = k[j] >= 0 ? k[j] : 0;
            int dhw = dhw_base + kj;
            float v0 = x[(size_t)(xb + 0 * DHW + dhw) * CC + lane];
            float v1 = x[(size_t)(xb + 1 * DHW + dhw) * CC + lane];
            float v2 = x[(size_t)(xb + 2 * DHW + dhw) * CC + lane];
            float v3 = x[(size_t)(xb + 3 * DHW + dhw) * CC + lane];
            val[j] = (v0 + v1) + (v2 + v3);
        }
        #pragma unroll
        for (int j = 0; j < 8; ++j) {                // wave-uniform merge
            if (cc[j] < 0) continue;
            if (cc[j] == cur) {
                acc += val[j];
            } else {
                if (cur >= 0) atomicAdd(&outT[(size_t)cur * CC + lane], acc);
                cur = cc[j];
                acc = val[j];
            }
        }
    }
    if (cur >= 0) atomicAdd(&outT[(size_t)cur * CC + lane], acc);

    // ---- slow path: views diverge (general inputs; never for this one) ----
    if (__ballot(!allsame)) {
        #pragma unroll
        for (int n = 0; n < NN; ++n) {
            unsigned long long m = __ballot((!allsame) && c4[n] >= 0);
            while (m) {
                int ks = __ffsll((long long)m) - 1;
                m &= m - 1ULL;
                int ck = __shfl(c4[n], ks);
                float xv = x[(size_t)(xb + n * DHW + dhw_base + ks) * CC + lane];
                atomicAdd(&outT[(size_t)ck * CC + lane], xv);
            }
        }
    }
}

// ---------------------------------------------------------------------------
// Transpose: outT [cell][ch] -> out [b][ch][yx]. 64x64 LDS tile padded to
// 65: coalesced 256B reads AND writes, bank-conflict-free. Fully overwrites
// out (no out memset). A 64-cell tile never straddles b (NYX % 64 == 0).
// ---------------------------------------------------------------------------
__global__ void __launch_bounds__(256)
transpose_kernel(const float* __restrict__ outT,
                 float* __restrict__ out) {
    __shared__ float tile[64][65];
    int tid      = threadIdx.x;
    int cellbase = blockIdx.x * 64;

    const float* src = outT + (size_t)cellbase * CC;
    #pragma unroll
    for (int i = 0; i < 16; ++i) {
        int idx = i * 256 + tid;                     // coalesced
        tile[idx >> 6][idx & 63] = src[idx];
    }
    __syncthreads();

    int bb     = cellbase / NYX;                     // uniform per block
    int yxbase = cellbase % NYX;
    float* dst = out + (size_t)bb * CC * NYX + yxbase;
    #pragma unroll
    for (int i = 0; i < 16; ++i) {
        int idx = i * 256 + tid;
        int ch  = idx >> 6;
        int cl  = idx & 63;
        dst[(size_t)ch * NYX + cl] = tile[cl][ch];   // stride-65: no conflicts
    }
}

// ---------------------------------------------------------------------------
extern "C" void kernel_launch(void* const* d_in, const int* in_sizes, int n_in,
                              void* d_out, int out_size, void* d_ws, size_t ws_size,
                              hipStream_t stream) {
    const float* x    = (const float*)d_in[0];
    const float* intr = (const float*)d_in[1];
    const float* pose = (const float*)d_in[2];
    float* out = (float*)d_out;

    double* coef = (double*)d_ws;                    // 8*12 doubles = 768 B
    float*  outT = (float*)d_ws + 256;               // NCELLS*CC = 18.9 MB

    hipMemsetAsync(outT, 0, (size_t)NCELLS * CC * sizeof(float), stream);
    setup_kernel<<<1, 64, 0, stream>>>(intr, pose, coef);
    scatter_kernel<<<QPTS / 128, 128, 0, stream>>>(x, coef, outT);
    transpose_kernel<<<NCELLS / 64, 256, 0, stream>>>(outT, out);
}

// Round 4
// 229.199 us; speedup vs baseline: 1.2053x; 1.0129x over previous
//
#include <hip/hip_runtime.h>

// Problem constants
#define BB 2
#define NN 4
#define DD 48
#define HH 28
#define WW 60
#define CC 64
#define NXg 192
#define NYg 192
#define NZg 1
#define DOWNS 8

constexpr int DHW    = DD * HH * WW;                 // 80640 rows per view
constexpr int NCELLS = BB * NZg * NYg * NXg;         // 73728 output cells
constexpr int NYX    = NYg * NXg;                    // 36864 cells per batch-plane
constexpr int GWAVES = BB * DD * WW;                 // 5760 (b,d,w) waves

// ---------------------------------------------------------------------------
// Setup: per-(b,n) f64 K-inverse + R*K^-1 combine, once (8 threads).
// [c00 c01 c02 c10 c11 c12 c20 c21 c22 tx ty tz] per view.
// ---------------------------------------------------------------------------
__global__ void setup_kernel(const float* __restrict__ intr,
                             const float* __restrict__ pose,
                             double* __restrict__ coef) {
    int i = threadIdx.x;
    if (i >= BB * NN) return;
    const float* K  = intr + (size_t)i * 9;
    const float* Pm = pose + (size_t)i * 16;

    double k00 = K[0], k01 = K[1], k02 = K[2];
    double k10 = K[3], k11 = K[4], k12 = K[5];
    double k20 = K[6], k21 = K[7], k22 = K[8];

    double det = k00 * (k11 * k22 - k12 * k21)
               - k01 * (k10 * k22 - k12 * k20)
               + k02 * (k10 * k21 - k11 * k20);
    double id = 1.0 / det;
    double i00 = (k11 * k22 - k12 * k21) * id;
    double i01 = (k02 * k21 - k01 * k22) * id;
    double i02 = (k01 * k12 - k02 * k11) * id;
    double i10 = (k12 * k20 - k10 * k22) * id;
    double i11 = (k00 * k22 - k02 * k20) * id;
    double i12 = (k02 * k10 - k00 * k12) * id;
    double i20 = (k10 * k21 - k11 * k20) * id;
    double i21 = (k01 * k20 - k00 * k21) * id;
    double i22 = (k00 * k11 - k01 * k10) * id;

    double r00 = Pm[0],  r01 = Pm[1],  r02 = Pm[2],  tx = Pm[3];
    double r10 = Pm[4],  r11 = Pm[5],  r12 = Pm[6],  ty = Pm[7];
    double r20 = Pm[8],  r21 = Pm[9],  r22 = Pm[10], tz = Pm[11];

    double* c = coef + (size_t)i * 12;
    c[0] = r00 * i00 + r01 * i10 + r02 * i20;
    c[1] = r00 * i01 + r01 * i11 + r02 * i21;
    c[2] = r00 * i02 + r01 * i12 + r02 * i22;
    c[3] = r10 * i00 + r11 * i10 + r12 * i20;
    c[4] = r10 * i01 + r11 * i11 + r12 * i21;
    c[5] = r10 * i02 + r11 * i12 + r12 * i22;
    c[6] = r20 * i00 + r21 * i10 + r22 * i20;
    c[7] = r20 * i01 + r21 * i11 + r22 * i21;
    c[8] = r20 * i02 + r21 * i12 + r22 * i22;
    c[9]  = tx;
    c[10] = ty;
    c[11] = tz;
}

// ---------------------------------------------------------------------------
// Scatter: ONE WAVE PER (b,d,w), lane = channel. With broadcast K/pose the
// cell is h-independent (B_x=B_y=0, detected at runtime), so the wave sums
// all kept h rows x all 4 views in registers (112 independent coalesced
// 256B loads, branchless mask-multiply) and emits ONE coalesced atomic run.
// ~161K lane-atomics total (100x below round 3). All geometry wave-uniform.
// General inputs fall into a run-merged per-h slow path.
// ---------------------------------------------------------------------------
__global__ void __launch_bounds__(256)
scatter_kernel(const float* __restrict__ x,
               const double* __restrict__ coef,
               float* __restrict__ outT) {
    int tid  = threadIdx.x;
    int lane = tid & 63;
    int gw   = blockIdx.x * 4 + (tid >> 6);          // grid exact multiple

    int w = gw % WW;
    int t = gw / WW;
    int d = t % DD;
    int b = t / DD;

    double u   = (double)w * ((double)(WW * DOWNS - 1) / (double)(WW - 1));
    double dep = 2.0 + (double)d;
    const double vstep = (double)(HH * DOWNS - 1) / (double)(HH - 1);

    // per-view: gx,gy affine in v; detect v-independence (B==0)
    int    cellv[4];
    double Az[4], Bz[4];
    bool   fastok = true;
    #pragma unroll
    for (int n = 0; n < NN; ++n) {
        const double* cf = coef + (size_t)(b * NN + n) * 12;
        double Bx = cf[1] * dep * 4.0;
        double By = cf[4] * dep * 4.0;
        if (Bx != 0.0 || By != 0.0) fastok = false;
        double gxf = ((cf[0] * u + cf[2]) * dep + cf[9])  * 4.0 + 96.0;
        double gyf = ((cf[3] * u + cf[5]) * dep + cf[10]) * 4.0 + 96.0;
        int gx = (int)gxf;
        int gy = (int)gyf;
        bool kxy = (gx >= 0) & (gx < NXg) & (gy >= 0) & (gy < NYg);
        cellv[n] = kxy ? ((b * NZg + 0) * NYg + gy) * NXg + gx : -1;  // gz=0 if kept
        Az[n] = ((cf[6] * u + cf[8]) * dep + cf[11] + 10.0) / 20.0;
        Bz[n] = cf[7] * dep * vstep / 20.0;          // per-h step in gz units
    }
    bool same = (cellv[0] == cellv[1]) & (cellv[1] == cellv[2]) &
                (cellv[2] == cellv[3]);

    // per-view h keep masks ((int)gzf == 0, matching reference truncation)
    unsigned hm[4];
    #pragma unroll
    for (int n = 0; n < NN; ++n) {
        unsigned m = 0;
        #pragma unroll
        for (int h = 0; h < HH; ++h) {
            double zf = Az[n] + Bz[n] * (double)h;
            int gz = (int)zf;                        // trunc toward 0, like astype
            m |= (gz == 0 ? 1u : 0u) << h;
        }
        hm[n] = m;
    }
    bool eqm = (hm[0] == hm[1]) & (hm[1] == hm[2]) & (hm[2] == hm[3]);

    size_t xrow = ((size_t)(b * NN) * DHW + (size_t)d * HH * WW + w) * CC + lane;

    if (fastok & same & eqm) {
        if (cellv[0] < 0 || hm[0] == 0u) return;
        unsigned m = hm[0];
        float acc = 0.f;
        #pragma unroll
        for (int h = 0; h < HH; ++h) {
            float s = ((m >> h) & 1u) ? 1.f : 0.f;   // wave-uniform mask
            size_t r = xrow + (size_t)(h * WW) * CC;
            float v0 = x[r + (size_t)(0 * DHW) * CC];
            float v1 = x[r + (size_t)(1 * DHW) * CC];
            float v2 = x[r + (size_t)(2 * DHW) * CC];
            float v3 = x[r + (size_t)(3 * DHW) * CC];
            acc += s * ((v0 + v1) + (v2 + v3));      // loads unconditional -> MLP
        }
        atomicAdd(&outT[(size_t)cellv[0] * CC + lane], acc);
        return;
    }

    // ---- general slow path: full per-h geometry, run-merged atomics ----
    float acc = 0.f;
    int   cur = -1;
    for (int n = 0; n < NN; ++n) {
        const double* cf = coef + (size_t)(b * NN + n) * 12;
        for (int h = 0; h < HH; ++h) {
            double v = (double)h * vstep;
            double gxf = ((cf[0] * u + cf[1] * v + cf[2]) * dep + cf[9])  * 4.0 + 96.0;
            double gyf = ((cf[3] * u + cf[4] * v + cf[5]) * dep + cf[10]) * 4.0 + 96.0;
            double gzf = ((cf[6] * u + cf[7] * v + cf[8]) * dep + cf[11] + 10.0) / 20.0;
            int gx = (int)gxf;
            int gy = (int)gyf;
            int gz = (int)gzf;
            bool kept = (gx >= 0) & (gx < NXg) & (gy >= 0) & (gy < NYg) &
                        (gz >= 0) & (gz < NZg);
            if (kept) {
                int cell = ((b * NZg + gz) * NYg + gy) * NXg + gx;
                float xv = x[xrow + (size_t)(n * DHW + h * WW) * CC];
                if (cell == cur) {
                    acc += xv;
                } else {
                    if (cur >= 0) atomicAdd(&outT[(size_t)cur * CC + lane], acc);
                    cur = cell;
                    acc = xv;
                }
            }
        }
    }
    if (cur >= 0) atomicAdd(&outT[(size_t)cur * CC + lane], acc);
}

// ---------------------------------------------------------------------------
// Transpose: outT [cell][ch] -> out [b][ch][yx]. 64x64 LDS tile padded to
// 65: coalesced 256B reads AND writes, bank-conflict-free. Fully overwrites
// out (no out memset). A 64-cell tile never straddles b (NYX % 64 == 0).
// ---------------------------------------------------------------------------
__global__ void __launch_bounds__(256)
transpose_kernel(const float* __restrict__ outT,
                 float* __restrict__ out) {
    __shared__ float tile[64][65];
    int tid      = threadIdx.x;
    int cellbase = blockIdx.x * 64;

    const float* src = outT + (size_t)cellbase * CC;
    #pragma unroll
    for (int i = 0; i < 16; ++i) {
        int idx = i * 256 + tid;                     // coalesced
        tile[idx >> 6][idx & 63] = src[idx];
    }
    __syncthreads();

    int bb     = cellbase / NYX;                     // uniform per block
    int yxbase = cellbase % NYX;
    float* dst = out + (size_t)bb * CC * NYX + yxbase;
    #pragma unroll
    for (int i = 0; i < 16; ++i) {
        int idx = i * 256 + tid;
        int ch  = idx >> 6;
        int cl  = idx & 63;
        dst[(size_t)ch * NYX + cl] = tile[cl][ch];   // stride-65: no conflicts
    }
}

// ---------------------------------------------------------------------------
extern "C" void kernel_launch(void* const* d_in, const int* in_sizes, int n_in,
                              void* d_out, int out_size, void* d_ws, size_t ws_size,
                              hipStream_t stream) {
    const float* x    = (const float*)d_in[0];
    const float* intr = (const float*)d_in[1];
    const float* pose = (const float*)d_in[2];
    float* out = (float*)d_out;

    double* coef = (double*)d_ws;                    // 8*12 doubles = 768 B
    float*  outT = (float*)d_ws + 256;               // NCELLS*CC = 18.9 MB

    hipMemsetAsync(outT, 0, (size_t)NCELLS * CC * sizeof(float), stream);
    setup_kernel<<<1, 64, 0, stream>>>(intr, pose, coef);
    scatter_kernel<<<GWAVES / 4, 256, 0, stream>>>(x, coef, outT);
    transpose_kernel<<<NCELLS / 64, 256, 0, stream>>>(outT, out);
}